// Round 3
// baseline (644.404 us; speedup 1.0000x reference)
//
#include <hip/hip_runtime.h>

#define B_CNT 4
#define N_CNT 10000
#define E_CNT 100000

typedef __attribute__((ext_vector_type(8))) short s16x8;
typedef __attribute__((ext_vector_type(4))) float f32x4;
typedef __attribute__((ext_vector_type(4))) unsigned int u32x4;

__device__ __forceinline__ float b2f(unsigned short u) {
  union { unsigned int i; float f; } v; v.i = ((unsigned int)u) << 16; return v.f;
}
__device__ __forceinline__ unsigned short f2b(float f) {
  union { float f; unsigned int i; } v; v.f = f;
  unsigned int b = v.i;
  b += 0x7FFFu + ((b >> 16) & 1u);   // round-to-nearest-even
  return (unsigned short)(b >> 16);
}
// packed fp32 pair -> bf16x2 (RNE), one VALU op
__device__ __forceinline__ unsigned int cvtpk(float lo, float hi) {
  unsigned int r;
  asm("v_cvt_pk_bf16_f32 %0, %1, %2" : "=v"(r) : "v"(lo), "v"(hi));
  return r;
}
// liveness pins: force values materialized (loads issued+completed) here
__device__ __forceinline__ void keepf4(const float4& v) {
  asm volatile("" :: "v"(v.x), "v"(v.y), "v"(v.z), "v"(v.w));
}
__device__ __forceinline__ void keeps(s16x8 v) {
  u32x4 u = __builtin_bit_cast(u32x4, v);
  asm volatile("" :: "v"(u.x), "v"(u.y), "v"(u.z), "v"(u.w));
}

// ---------------------------------------------------------------------------
// K1: spectral transform (closed-form rfft/irfft over batch axis, n=4).
// ---------------------------------------------------------------------------
__global__ void k_fft(const float* __restrict__ x,
                      const float* __restrict__ tcwr,
                      const float* __restrict__ tcwi,
                      float* __restrict__ xnew) {
  __shared__ float Wr[256], Wi[256];
  const int t = threadIdx.x;
  Wr[t] = tcwr[t * 2] + tcwr[t * 2 + 1];
  Wi[t] = tcwi[t * 2] + tcwi[t * 2 + 1];
  __syncthreads();
  const int n = blockIdx.x * 256 + t;
  if (n >= N_CNT) return;

  float xt[4][16];
  for (int tt = 0; tt < 4; ++tt) {
    const float* xp = x + ((size_t)tt * N_CNT + n) * 16;
#pragma unroll
    for (int i0 = 0; i0 < 16; i0 += 4) {
      const float4 v = *(const float4*)(xp + i0);
      xt[tt][i0 + 0] = v.x; xt[tt][i0 + 1] = v.y;
      xt[tt][i0 + 2] = v.z; xt[tt][i0 + 3] = v.w;
    }
  }
  float s[16], a[16], bb[16];
#pragma unroll
  for (int i = 0; i < 16; ++i) {
    s[i]  = xt[0][i] + xt[1][i] + xt[2][i] + xt[3][i];
    a[i]  = xt[0][i] - xt[2][i];
    bb[i] = xt[1][i] - xt[3][i];
  }
  for (int o = 0; o < 16; ++o) {
    float r0 = 0.f, p = 0.f, qq = 0.f;
#pragma unroll
    for (int i = 0; i < 16; ++i) {
      const float wr = Wr[i * 16 + o], wi = Wi[i * 16 + o];
      r0 += s[i] * wr;
      p  += a[i] * wr + bb[i] * wi;
      qq += a[i] * wi - bb[i] * wr;
    }
    xnew[((size_t)0 * N_CNT + n) * 16 + o] = 0.25f * (r0 + 2.f * p);
    xnew[((size_t)1 * N_CNT + n) * 16 + o] = 0.25f * (r0 - 2.f * qq);
    xnew[((size_t)2 * N_CNT + n) * 16 + o] = 0.25f * (r0 - 2.f * p);
    xnew[((size_t)3 * N_CNT + n) * 16 + o] = 0.25f * (r0 + 2.f * qq);
  }
}

// ---------------------------------------------------------------------------
// K2: pack W1 (128x128) and W2 (128x384) fp32 -> bf16 MFMA B-fragment order.
// pw2 w1-part (nt<16): col = nt*16+lm  (i=nt, o=lm).
// pw2 w2-part (nt>=16): col = 256 + (8*(lm&1)+(nt-16))*8 + (lm>>1)
// ---------------------------------------------------------------------------
__global__ void k_pack(const float* __restrict__ w1,
                       const float* __restrict__ w2,
                       unsigned short* __restrict__ pw1,
                       unsigned short* __restrict__ pw2) {
  const int t = blockIdx.x * 256 + threadIdx.x;  // 0..8191
  const int tile = t >> 6, l = t & 63, q = l >> 4, lm = l & 15;
  if (tile < 32) {
    const int nt = tile >> 2, kk = tile & 3;
    const int n = nt * 16 + lm;
    unsigned short* dst = pw1 + ((size_t)tile * 64 + l) * 8;
#pragma unroll
    for (int j = 0; j < 8; ++j) dst[j] = f2b(w1[(kk * 32 + q * 8 + j) * 128 + n]);
  } else {
    const int t2 = tile - 32;  // 0..95
    const int nt = t2 >> 2, kk = t2 & 3;
    int col;
    if (nt < 16) col = nt * 16 + lm;
    else col = 256 + (8 * (lm & 1) + (nt - 16)) * 8 + (lm >> 1);
    unsigned short* dst = pw2 + ((size_t)t2 * 64 + l) * 8;
#pragma unroll
    for (int j = 0; j < 8; ++j) dst[j] = f2b(w2[(kk * 32 + q * 8 + j) * 384 + col]);
  }
}

// ---------------------------------------------------------------------------
// K3: per-node in-degree histogram.
// ---------------------------------------------------------------------------
__global__ void k_cnt(const int* __restrict__ eidx, int* __restrict__ cnt) {
  const int e = blockIdx.x * 256 + threadIdx.x;
  if (e < E_CNT) atomicAdd(&cnt[eidx[E_CNT + e]], 1);
}

// ---------------------------------------------------------------------------
// K3b: exclusive prefix scan of cnt -> rowstart[10001], runoff copy.
// ---------------------------------------------------------------------------
__global__ void k_scan(const int* __restrict__ cnt, int* __restrict__ rowstart,
                       int* __restrict__ runoff) {
  __shared__ int partial[256];
  const int t = threadIdx.x;
  const int c0 = t * 40;
  int s = 0;
  for (int j = 0; j < 40; ++j) {
    const int idx = c0 + j;
    if (idx < N_CNT) s += cnt[idx];
  }
  partial[t] = s;
  __syncthreads();
  if (t == 0) {
    int acc = 0;
    for (int i = 0; i < 256; ++i) { const int v = partial[i]; partial[i] = acc; acc += v; }
  }
  __syncthreads();
  int acc = partial[t];
  for (int j = 0; j < 40; ++j) {
    const int idx = c0 + j;
    if (idx < N_CNT) { rowstart[idx] = acc; runoff[idx] = acc; acc += cnt[idx]; }
  }
  if (t == 255) rowstart[N_CNT] = acc;  // == E_CNT
}

// ---------------------------------------------------------------------------
// K3c: per-edge slot assignment within its dst group (CSR permutation).
// ---------------------------------------------------------------------------
__global__ void k_pos(const int* __restrict__ eidx, int* __restrict__ runoff,
                      int* __restrict__ pos) {
  const int e = blockIdx.x * 256 + threadIdx.x;
  if (e < E_CNT) pos[e] = atomicAdd(&runoff[eidx[E_CNT + e]], 1);
}

// ---------------------------------------------------------------------------
// K4: fused edge kernel. Per block: 32 edges, one batch.
//   GEMM1: H(32x128) = relu(EA @ W1 + b1)  (all A+B loads issued, pinned, then MFMA)
//   GEMM2: EW(32x384) = H @ W2 + b2
//   EWt LDS layout [edge][24ch][2 halves of 8 bf16], HALF-SWIZZLED:
//     physical half = logical half ^ ((edge>>2)&1)   (q&1 on the store side)
//   -> w1-part b32 stores drop from 16-way to 8-way bank conflict (floor).
//   phase 3: 24 dots/edge, b128 LDS reads (half-swapped), plain stores (CSR).
// ---------------------------------------------------------------------------
template <bool ATOMIC>
__global__ __launch_bounds__(256, 4) void k_edge(
    const float* __restrict__ ea, const int* __restrict__ eidx,
    const float* __restrict__ esh,
    const unsigned short* __restrict__ pw1, const unsigned short* __restrict__ pw2,
    const float* __restrict__ b1v, const float* __restrict__ b2v,
    const float* __restrict__ xnew, const int* __restrict__ idx_arr,
    float* __restrict__ out_base, const size_t bstride) {
  __shared__ __align__(16) unsigned short Hs[32 * 136];   // [edge][k], +8 pad
  __shared__ __align__(16) unsigned short EWt[32 * 392];  // [edge][24ch][16i], +8 pad
  __shared__ float xgs[32 * 20];                          // 16 + 4 pad
  __shared__ float shs[32 * 4];
  __shared__ int ids[32];

  const int t = threadIdx.x;
  const int b = blockIdx.y;
  const int e0 = blockIdx.x * 32;
  const int w = t >> 6, l = t & 63, q = l >> 4, lm = l & 15;

  // ---- phase 0: stage xg (gather), sh, row ids ----
  if (t < 128) {
    const int el = t >> 2, i0 = (t & 3) * 4;
    const int src = eidx[e0 + el];
    const float4 v = *(const float4*)(xnew + ((size_t)b * N_CNT + src) * 16 + i0);
    xgs[el * 20 + i0 + 0] = v.x;
    xgs[el * 20 + i0 + 1] = v.y;
    xgs[el * 20 + i0 + 2] = v.z;
    xgs[el * 20 + i0 + 3] = v.w;
  } else if (t < 160) {
    const int el = t - 128;
    const float4 v = *(const float4*)(esh + ((size_t)b * E_CNT + e0 + el) * 4);
    shs[el * 4 + 0] = v.x;
    shs[el * 4 + 1] = v.y;
    shs[el * 4 + 2] = v.z;
    shs[el * 4 + 3] = v.w;
  } else if (t < 192) {
    const int el = t - 160;
    ids[el] = idx_arr[e0 + el];
  }

  // ---- GEMM1: issue ALL A-loads (HBM) then all B-frags (L2), pin, then MFMA ----
  const float* eab = ea + (size_t)b * E_CNT * 128;
  float4 araw[4][2][2];
#pragma unroll
  for (int kk = 0; kk < 4; ++kk)
#pragma unroll
    for (int mt = 0; mt < 2; ++mt) {
      const float* ap = eab + ((size_t)(e0 + mt * 16 + lm)) * 128 + kk * 32 + q * 8;
      araw[kk][mt][0] = *(const float4*)ap;
      araw[kk][mt][1] = *(const float4*)(ap + 4);
    }
  s16x8 bfr[2][4];
#pragma unroll
  for (int j = 0; j < 2; ++j)
#pragma unroll
    for (int kk = 0; kk < 4; ++kk)
      bfr[j][kk] = *(const s16x8*)(pw1 + (((size_t)(2 * w + j) * 4 + kk) * 64 + l) * 8);
  // pin: all loads issued above must be live here (issue-all / wait-once)
#pragma unroll
  for (int kk = 0; kk < 4; ++kk)
#pragma unroll
    for (int mt = 0; mt < 2; ++mt) { keepf4(araw[kk][mt][0]); keepf4(araw[kk][mt][1]); }
#pragma unroll
  for (int j = 0; j < 2; ++j)
#pragma unroll
    for (int kk = 0; kk < 4; ++kk) keeps(bfr[j][kk]);

  f32x4 acc1[2][2];
#pragma unroll
  for (int mt = 0; mt < 2; ++mt)
#pragma unroll
    for (int j = 0; j < 2; ++j) acc1[mt][j] = (f32x4)0.0f;

#pragma unroll
  for (int kk = 0; kk < 4; ++kk) {
#pragma unroll
    for (int mt = 0; mt < 2; ++mt) {
      const float4 a0 = araw[kk][mt][0];
      const float4 a1 = araw[kk][mt][1];
      union { unsigned int u[4]; s16x8 s; } au;
      au.u[0] = cvtpk(a0.x, a0.y); au.u[1] = cvtpk(a0.z, a0.w);
      au.u[2] = cvtpk(a1.x, a1.y); au.u[3] = cvtpk(a1.z, a1.w);
      const s16x8 af = au.s;
      acc1[mt][0] = __builtin_amdgcn_mfma_f32_16x16x32_bf16(af, bfr[0][kk], acc1[mt][0], 0, 0, 0);
      acc1[mt][1] = __builtin_amdgcn_mfma_f32_16x16x32_bf16(af, bfr[1][kk], acc1[mt][1], 0, 0, 0);
    }
  }

  // prefetch GEMM2 B-fragments for kk=0 (independent of Hs)
  s16x8 bw0[6];
#pragma unroll
  for (int jj = 0; jj < 6; ++jj)
    bw0[jj] = *(const s16x8*)(pw2 + (((size_t)(6 * w + jj) * 4 + 0) * 64 + l) * 8);

  // ---- GEMM1 epilogue: bias+relu, pair-convert, scalar Hs stores ----
#pragma unroll
  for (int j = 0; j < 2; ++j) {
    const int n = (2 * w + j) * 16 + lm;
    const float bias = b1v[n];
#pragma unroll
    for (int mt = 0; mt < 2; ++mt) {
#pragma unroll
      for (int r = 0; r < 4; r += 2) {
        const float v0 = fmaxf(acc1[mt][j][r] + bias, 0.0f);
        const float v1 = fmaxf(acc1[mt][j][r + 1] + bias, 0.0f);
        const unsigned int pr = cvtpk(v0, v1);
        Hs[(mt * 16 + q * 4 + r) * 136 + n] = (unsigned short)pr;
        Hs[(mt * 16 + q * 4 + r + 1) * 136 + n] = (unsigned short)(pr >> 16);
      }
    }
  }
#pragma unroll
  for (int jj = 0; jj < 6; ++jj) keeps(bw0[jj]);   // pin across barrier
  __syncthreads();

  // ---- GEMM2 ----
  f32x4 acc2[2][6];
#pragma unroll
  for (int mt = 0; mt < 2; ++mt)
#pragma unroll
    for (int jj = 0; jj < 6; ++jj) acc2[mt][jj] = (f32x4)0.0f;

#pragma unroll
  for (int kk = 0; kk < 4; ++kk) {
    s16x8 bw[6];
    if (kk == 0) {
#pragma unroll
      for (int jj = 0; jj < 6; ++jj) bw[jj] = bw0[jj];
    } else {
#pragma unroll
      for (int jj = 0; jj < 6; ++jj)
        bw[jj] = *(const s16x8*)(pw2 + (((size_t)(6 * w + jj) * 4 + kk) * 64 + l) * 8);
    }
#pragma unroll
    for (int mt = 0; mt < 2; ++mt) {
      const s16x8 ah = *(const s16x8*)(&Hs[(mt * 16 + lm) * 136 + kk * 32 + q * 8]);
#pragma unroll
      for (int jj = 0; jj < 6; ++jj)
        acc2[mt][jj] = __builtin_amdgcn_mfma_f32_16x16x32_bf16(ah, bw[jj], acc2[mt][jj], 0, 0, 0);
    }
  }

  // ---- epilogue 2: bias + cvt_pk, HALF-SWIZZLED b32 stores ----
  // logical: tile T=6w+jj: T<16 -> (ch=lm, i=T); T>=16 -> (ch=16+(lm>>1), i=8*(l&1)+T-16)
  // physical 16B-half = logical half ^ (q&1)  [= (edge>>2)&1 for this lane's edges]
  float bias6[6];
#pragma unroll
  for (int jj = 0; jj < 6; ++jj) {
    const int T = 6 * w + jj;
    const int bcol = (T < 16) ? (T * 16 + lm)
                              : (256 + (8 * (l & 1) + (T - 16)) * 8 + (lm >> 1));
    bias6[jj] = b2v[bcol];
  }
  const int sq4 = (q & 1) * 4;          // swizzle offset for half 0
  const int nsq4 = 4 - sq4;             // swizzle offset for half 1
  const int ch2off = (16 + (lm >> 1)) * 8 + (((l & 1) ^ (q & 1)) ? 4 : 0);
#pragma unroll
  for (int mt = 0; mt < 2; ++mt)
#pragma unroll
    for (int r = 0; r < 4; ++r) {
      const int edge = mt * 16 + q * 4 + r;
      const unsigned int p0 = cvtpk(acc2[mt][0][r] + bias6[0], acc2[mt][1][r] + bias6[1]);
      const unsigned int p1 = cvtpk(acc2[mt][2][r] + bias6[2], acc2[mt][3][r] + bias6[3]);
      const unsigned int p2 = cvtpk(acc2[mt][4][r] + bias6[4], acc2[mt][5][r] + bias6[5]);
      unsigned int* base = (unsigned int*)&EWt[edge * 392];
      if (w == 0) {                      // dwords 0,1,2 of ch=lm (half0 pos0-2)
        unsigned int* d = base + lm * 8 + sq4;
        d[0] = p0; d[1] = p1; d[2] = p2;
      } else if (w == 1) {               // dword3 (h0p3), dwords 4,5 (h1 p0,1)
        base[lm * 8 + sq4 + 3] = p0;
        unsigned int* d = base + lm * 8 + nsq4;
        d[0] = p1; d[1] = p2;
      } else if (w == 2) {               // dwords 6,7 (h1 p2,3); ch2 h=(l&1) p0
        unsigned int* d = base + lm * 8 + nsq4 + 2;
        d[0] = p0; d[1] = p1;
        base[ch2off] = p2;
      } else {                           // ch2 h=(l&1) pos 1,2,3
        unsigned int* d = base + ch2off + 1;
        d[0] = p0; d[1] = p1; d[2] = p2;
      }
    }
  __syncthreads();

  // ---- phase 3: 24 dots/edge, 3 per thread, half-swapped b128 LDS reads ----
  {
    const int m = t >> 3, sub = t & 7;
    const int sqr8 = ((m >> 2) & 1) << 3;    // read-side half swap
    float xr[16];
#pragma unroll
    for (int i0 = 0; i0 < 16; i0 += 4) {
      const float4 v = *(const float4*)&xgs[m * 20 + i0];
      xr[i0] = v.x; xr[i0 + 1] = v.y; xr[i0 + 2] = v.z; xr[i0 + 3] = v.w;
    }
    const float sh0v = 0.25f * shs[m * 4 + 0];   // ALPHA = 1/sqrt(16)
    const float s1a = 0.25f * shs[m * 4 + 1];
    const float s1b = 0.25f * shs[m * 4 + 2];
    const float s1c = 0.25f * shs[m * 4 + 3];
    float* outp = out_base + (size_t)b * bstride + (size_t)ids[m] * 40;
#pragma unroll
    for (int dd = 0; dd < 3; ++dd) {
      const int d = sub * 3 + dd;                // 0..23 == EWt channel
      const unsigned short* ep = &EWt[m * 392 + d * 16];
      const s16x8 eA = *(const s16x8*)(ep + sqr8);
      const s16x8 eB = *(const s16x8*)(ep + 8 - sqr8);
      float dotv = 0.f;
#pragma unroll
      for (int i = 0; i < 8; ++i) {
        dotv += xr[i] * b2f((unsigned short)eA[i]);
        dotv += xr[8 + i] * b2f((unsigned short)eB[i]);
      }
      if (d < 16) {
        const float val = dotv * sh0v;
        if (ATOMIC) atomicAdd(outp + d, val); else outp[d] = val;
      } else {
        const int c0 = 16 + (d - 16) * 3;
        if (ATOMIC) {
          atomicAdd(outp + c0 + 0, dotv * s1a);
          atomicAdd(outp + c0 + 1, dotv * s1b);
          atomicAdd(outp + c0 + 2, dotv * s1c);
        } else {
          outp[c0 + 0] = dotv * s1a;
          outp[c0 + 1] = dotv * s1b;
          outp[c0 + 2] = dotv * s1c;
        }
      }
    }
  }
}

// ---------------------------------------------------------------------------
// K5 (fallback only): agg = sums / max(cnt,1) + per-channel partials.
// ---------------------------------------------------------------------------
__global__ void k_agg(float* __restrict__ sums, const int* __restrict__ cnt,
                      float* __restrict__ psum, float* __restrict__ psq) {
  __shared__ float ls[40], lq[40];
  const int t = threadIdx.x;
  if (t < 40) { ls[t] = 0.f; lq[t] = 0.f; }
  __syncthreads();
  const unsigned base = blockIdx.x * 2048u + t;
  for (int k2 = 0; k2 < 8; ++k2) {
    const unsigned idx = base + k2 * 256u;
    if (idx < 1600000u) {
      const unsigned row = idx / 40u;
      const unsigned node = row % 10000u;
      const float c = (float)cnt[node];
      const float v = sums[idx] / fmaxf(c, 1.f);
      sums[idx] = v;
      const unsigned ch = idx - row * 40u;
      atomicAdd(&ls[ch], v);
      atomicAdd(&lq[ch], v * v);
    }
  }
  __syncthreads();
  if (t < 40) {
    atomicAdd(&psum[t], ls[t]);
    atomicAdd(&psq[t], lq[t]);
  }
}

// ---------------------------------------------------------------------------
// K5b (CSR): gather rows per (b,node), mean-divide, BN partials.
// 8 pairs/wave (grid 1250), unroll-by-4 independent accumulators.
// ---------------------------------------------------------------------------
__global__ __launch_bounds__(256) void k_gather(
    const float* __restrict__ msgbuf, const int* __restrict__ rowstart,
    float* __restrict__ sums, float* __restrict__ psum, float* __restrict__ psq) {
  const int t = threadIdx.x;
  const int wid = t >> 6, ch = t & 63;
  if (ch >= 40) return;
  float lsum = 0.f, lsq = 0.f;
  for (int k = 0; k < 8; ++k) {
    const int p = blockIdx.x * 32 + wid * 8 + k;   // 0..39999 = b*10000+node
    const int bb = p / 10000;
    const int node = p - bb * 10000;
    const int r0 = rowstart[node], r1 = rowstart[node + 1];
    const float* base = msgbuf + (size_t)bb * (E_CNT * 40) + ch;
    float v0 = 0.f, v1 = 0.f, v2 = 0.f, v3 = 0.f;
    int r = r0;
    for (; r + 4 <= r1; r += 4) {
      v0 += base[(size_t)(r + 0) * 40];
      v1 += base[(size_t)(r + 1) * 40];
      v2 += base[(size_t)(r + 2) * 40];
      v3 += base[(size_t)(r + 3) * 40];
    }
    for (; r < r1; ++r) v0 += base[(size_t)r * 40];
    float v = (v0 + v1) + (v2 + v3);
    v /= fmaxf((float)(r1 - r0), 1.f);
    sums[(size_t)p * 40 + ch] = v;
    lsum += v; lsq += v * v;
  }
  atomicAdd(&psum[ch], lsum);
  atomicAdd(&psq[ch], lsq);
}

// ---------------------------------------------------------------------------
// K7: BN finalize (per-block, from partials) + normalize + fp32 output.
// ---------------------------------------------------------------------------
__global__ void k_out(const float* __restrict__ agg,
                      const float* __restrict__ psum, const float* __restrict__ psq,
                      const float* __restrict__ gma, const float* __restrict__ bta,
                      float* __restrict__ outp) {
  __shared__ float sc[40], sh[40];
  const int t = threadIdx.x;
  if (t < 40) {
    const float inv = 1.0f / 40000.0f;  // B*N rows
    const float mu = psum[t] * inv;
    const float var = psq[t] * inv - mu * mu;
    const float s = rsqrtf(fmaxf(var, 0.0f) + 1e-5f) * gma[t];
    sc[t] = s;
    sh[t] = bta[t] - mu * s;
  }
  __syncthreads();
  const unsigned base = blockIdx.x * 1024u + t;
#pragma unroll
  for (int k2 = 0; k2 < 4; ++k2) {
    const unsigned idx = base + k2 * 256u;
    if (idx < 1600000u) {
      const unsigned row = idx / 40u;
      const unsigned ch = idx - row * 40u;
      outp[idx] = agg[idx] * sc[ch] + sh[ch];
    }
  }
}

// ---------------------------------------------------------------------------
// Workspace layout (bytes):
//   [0)          sums      6,400,000   (CSR: written by k_gather; FB: zeroed)
//   [6,400,000)  cnt          40,000   (zeroed)
//   [6,440,000)  psum            160   (zeroed)
//   [6,440,160)  psq             160   (zeroed)
//   [6,440,448)  xnew      2,560,000
//   [9,000,448)  pw1          32,768
//   [9,033,216)  pw2          98,304
//   [9,131,840)  rowstart     40,016   (10001 ints)           } CSR only
//   [9,171,856)  runoff       40,000                          }
//   [9,211,856)  pos         400,000                          }
//   [9,611,904)  msgbuf   64,000,000                          }
// ---------------------------------------------------------------------------
extern "C" void kernel_launch(void* const* d_in, const int* in_sizes, int n_in,
                              void* d_out, int out_size, void* d_ws, size_t ws_size,
                              hipStream_t stream) {
  (void)in_sizes; (void)n_in; (void)out_size;
  const float* x    = (const float*)d_in[0];
  const int*   eidx = (const int*)d_in[1];
  const float* ea   = (const float*)d_in[2];
  const float* esh  = (const float*)d_in[3];
  const float* tcwr = (const float*)d_in[4];
  const float* tcwi = (const float*)d_in[5];
  const float* w1   = (const float*)d_in[6];
  const float* b1   = (const float*)d_in[7];
  const float* w2   = (const float*)d_in[8];
  const float* b2   = (const float*)d_in[9];
  const float* gma  = (const float*)d_in[10];
  const float* bta  = (const float*)d_in[11];

  char* ws = (char*)d_ws;
  float*          sums     = (float*)(ws + 0);
  int*            cnt      = (int*)(ws + 6400000);
  float*          psum     = (float*)(ws + 6440000);
  float*          psq      = (float*)(ws + 6440160);
  float*          xnew     = (float*)(ws + 6440448);
  unsigned short* pw1      = (unsigned short*)(ws + 9000448);
  unsigned short* pw2      = (unsigned short*)(ws + 9033216);
  int*            rowstart = (int*)(ws + 9131840);
  int*            runoff   = (int*)(ws + 9171856);
  int*            pos      = (int*)(ws + 9211856);
  float*          msgbuf   = (float*)(ws + 9611904);

  const bool use_csr = ws_size >= (size_t)73611904;

  if (use_csr) {
    hipMemsetAsync(ws + 6400000, 0, 40320, stream);  // cnt + psum + psq
    k_fft<<<dim3(40), dim3(256), 0, stream>>>(x, tcwr, tcwi, xnew);
    k_pack<<<dim3(32), dim3(256), 0, stream>>>(w1, w2, pw1, pw2);
    k_cnt<<<dim3(391), dim3(256), 0, stream>>>(eidx, cnt);
    k_scan<<<dim3(1), dim3(256), 0, stream>>>(cnt, rowstart, runoff);
    k_pos<<<dim3(391), dim3(256), 0, stream>>>(eidx, runoff, pos);
    k_edge<false><<<dim3(E_CNT / 32, B_CNT), dim3(256), 0, stream>>>(
        ea, eidx, esh, pw1, pw2, b1, b2, xnew, pos, msgbuf, (size_t)E_CNT * 40);
    k_gather<<<dim3(1250), dim3(256), 0, stream>>>(msgbuf, rowstart, sums, psum, psq);
    k_out<<<dim3(1563), dim3(256), 0, stream>>>(sums, psum, psq, gma, bta, (float*)d_out);
  } else {
    hipMemsetAsync(ws, 0, 6440320, stream);
    k_fft<<<dim3(40), dim3(256), 0, stream>>>(x, tcwr, tcwi, xnew);
    k_pack<<<dim3(32), dim3(256), 0, stream>>>(w1, w2, pw1, pw2);
    k_cnt<<<dim3(391), dim3(256), 0, stream>>>(eidx, cnt);
    k_edge<true><<<dim3(E_CNT / 32, B_CNT), dim3(256), 0, stream>>>(
        ea, eidx, esh, pw1, pw2, b1, b2, xnew, eidx + E_CNT, sums, (size_t)N_CNT * 40);
    k_agg<<<dim3(782), dim3(256), 0, stream>>>(sums, cnt, psum, psq);
    k_out<<<dim3(1563), dim3(256), 0, stream>>>(sums, psum, psq, gma, bta, (float*)d_out);
  }
}